// Round 11
// baseline (186.822 us; speedup 1.0000x reference)
//
#include <hip/hip_runtime.h>

// Problem constants (B=1 throughout)
#define SC 6       // cameras
#define NQ 6400    // queries
#define CH 128     // channels
#define HSY 32     // feature H
#define WSX 88     // feature W
#define MV 2816    // HSY*WSX
#define NH 4       // heads
#define NP 20      // points
#define DD 4       // Z anchors (D)
#define DHC 32     // CH/NH
#define NPG 5      // NP/DD
#define NPAIR (SC * NH * NP)   // 480 (cam,head,point) pairs per query

// mega-kernel block roles
#define QB2 16
#define VB2 32
#define NB_QPROJ (NQ / QB2)            // 400
#define NB_VPROJ (SC * MV / VB2)       // 528
#define NB_MEGA  (1 + NB_QPROJ + NB_VPROJ)

// ---------------- workspace layout (float indices) ----------------
#define WS_QOFF     38464
#define WS_AW       1062464
#define WS_VAL      1574464

__device__ __forceinline__ unsigned short f32_to_bf16(float x) {
    unsigned int u = __float_as_uint(x);
    unsigned int r = (u + 0x7FFFu + ((u >> 16) & 1u)) >> 16;   // RNE
    return (unsigned short)r;
}

// ---------------- K1: mega (detect | qproj | vproj), LDS-staged weights ----------------
// smem union (float indices):
//   qproj: qs[128][16] @0 (2048) | wst[7680] @2048 | lg[16][80] @9728  -> 11008
//   vproj: vs[128][36] @0 (4608, padded rows) | wvt[4096] @4608       -> 8704
//   detect: 512 uints @0
__global__ __launch_bounds__(256) void k_mega(
        const unsigned int* __restrict__ bm,
        const float* __restrict__ q, const float* __restrict__ qpos,
        const float* __restrict__ Woff, const float* __restrict__ boff,
        const float* __restrict__ Wattn, const float* __restrict__ battn,
        const float* __restrict__ value, const float* __restrict__ Wv,
        const float* __restrict__ bv,
        int* __restrict__ flag, float* __restrict__ qoff,
        float* __restrict__ aw, unsigned short* __restrict__ valw) {
    __shared__ __align__(16) float smem[11008];   // 43 KB
    int bid = blockIdx.x;
    int t = threadIdx.x;

    if (bid == 0) {
        // ---- detection: scan first 2048 words (safe under all 3 layouts) ----
        unsigned int* r_or = (unsigned int*)smem;
        unsigned int* r_vi = r_or + 256;
        unsigned int o = 0u, v = 0u;
        for (int i = t; i < 2048; i += 256) {
            unsigned int w = bm[i];
            o |= (w & 0xFFFFFF00u);
            v |= (unsigned int)((w != 0u) & (w != 0x3F800000u));
        }
        r_or[t] = o; r_vi[t] = v;
        __syncthreads();
        for (int s = 128; s > 0; s >>= 1) {
            if (t < s) { r_or[t] |= r_or[t + s]; r_vi[t] |= r_vi[t + s]; }
            __syncthreads();
        }
        if (t == 0) {
            int f;
            if (!r_vi[0]) f = 2;          // float32 (or all-zero)
            else if (r_or[0]) f = 1;      // byte-packed bool
            else f = 0;                   // int32
            *flag = f;
        }
        return;
    }

    if (bid <= NB_QPROJ) {
        // ---- query projections + softmax, 16 queries/block, staged weights ----
        float (*qs)[QB2] = (float(*)[QB2])smem;                  // [128][16]
        float* wst = smem + 2048;                                // 7680: Woff[32][160] | Wattn[32][80]
        float (*lg)[NH * NP] = (float(*)[NH * NP])(smem + 9728); // [16][80]
        int n0 = (bid - 1) * QB2;
        for (int i = t; i < QB2 * CH; i += 256) {
            int qi = i >> 7, k = i & 127;
            int gi = (n0 + qi) * CH + k;
            qs[k][qi] = q[gi] + qpos[gi];
        }
        float acc[QB2];
#pragma unroll
        for (int qi = 0; qi < QB2; ++qi) acc[qi] = 0.f;

        for (int kc = 0; kc < 4; ++kc) {
            // stage 32 k-rows of Woff and Wattn (coalesced)
            for (int j = t; j < 5120; j += 256) {
                int kk = j / 160, cc = j - kk * 160;
                wst[j] = Woff[(kc * 32 + kk) * 160 + cc];
            }
            for (int j = t; j < 2560; j += 256) {
                int kk = j / 80, cc = j - kk * 80;
                wst[5120 + j] = Wattn[(kc * 32 + kk) * 80 + cc];
            }
            __syncthreads();
            if (t < 160) {
                for (int kk = 0; kk < 32; ++kk) {
                    float w = wst[kk * 160 + t];
                    const float* qrow = &qs[kc * 32 + kk][0];
#pragma unroll
                    for (int v4 = 0; v4 < QB2 / 4; ++v4) {
                        float4 a = *(const float4*)(qrow + v4 * 4);
                        acc[v4 * 4 + 0] += a.x * w; acc[v4 * 4 + 1] += a.y * w;
                        acc[v4 * 4 + 2] += a.z * w; acc[v4 * 4 + 3] += a.w * w;
                    }
                }
            } else if (t < 240) {
                int j = t - 160;
                for (int kk = 0; kk < 32; ++kk) {
                    float w = wst[5120 + kk * 80 + j];
                    const float* qrow = &qs[kc * 32 + kk][0];
#pragma unroll
                    for (int v4 = 0; v4 < QB2 / 4; ++v4) {
                        float4 a = *(const float4*)(qrow + v4 * 4);
                        acc[v4 * 4 + 0] += a.x * w; acc[v4 * 4 + 1] += a.y * w;
                        acc[v4 * 4 + 2] += a.z * w; acc[v4 * 4 + 3] += a.w * w;
                    }
                }
            }
            __syncthreads();
        }
        if (t < 160) {
            float b = boff[t];
#pragma unroll
            for (int qi = 0; qi < QB2; ++qi) qoff[(n0 + qi) * 160 + t] = acc[qi] + b;
        } else if (t < 240) {
            int j = t - 160;
            float b = battn[j];
#pragma unroll
            for (int qi = 0; qi < QB2; ++qi) lg[qi][j] = acc[qi] + b;
        }
        __syncthreads();
        if (t < QB2 * NH) {
            int qi = t >> 2, h = t & 3;
            float mx = -1e30f;
#pragma unroll
            for (int p = 0; p < NP; ++p) mx = fmaxf(mx, lg[qi][h * NP + p]);
            float e[NP];
            float sm = 0.f;
#pragma unroll
            for (int p = 0; p < NP; ++p) { e[p] = __expf(lg[qi][h * NP + p] - mx); sm += e[p]; }
            float inv = 1.f / sm;
#pragma unroll
            for (int p = 0; p < NP; ++p) aw[(n0 + qi) * 80 + h * NP + p] = e[p] * inv;
        }
        return;
    }

    // ---- value projection -> bf16 (s,h,m,dh), 32 rows/block, staged weights ----
    {
        float* vs = smem;                 // [128][36] padded rows (4608)
        float* wvt = smem + 4608;         // [32][128] chunk
        int r0 = (bid - 1 - NB_QPROJ) * VB2;
        for (int i = t; i < VB2 * CH; i += 256) {
            int ri = i >> 7, k = i & 127;     // coalesced global read
            vs[k * 36 + ri] = value[(size_t)(r0 + ri) * CH + k];
        }
        int c = t & 127, rh = t >> 7;    // rh: row half (0: rows 0-15, 1: rows 16-31)
        float acc[16];
#pragma unroll
        for (int ri = 0; ri < 16; ++ri) acc[ri] = 0.f;

        for (int kc = 0; kc < 4; ++kc) {
            for (int j = t; j < 4096; j += 256) {
                wvt[j] = Wv[(kc * 32 + (j >> 7)) * 128 + (j & 127)];   // coalesced
            }
            __syncthreads();
            for (int kk = 0; kk < 32; ++kk) {
                float w = wvt[kk * 128 + c];
                const float* vrow = vs + (kc * 32 + kk) * 36 + rh * 16;
#pragma unroll
                for (int v4 = 0; v4 < 4; ++v4) {
                    float4 a = *(const float4*)(vrow + v4 * 4);
                    acc[v4 * 4 + 0] += a.x * w; acc[v4 * 4 + 1] += a.y * w;
                    acc[v4 * 4 + 2] += a.z * w; acc[v4 * 4 + 3] += a.w * w;
                }
            }
            __syncthreads();
        }
        float b = bv[c];
        int h = c >> 5, dh = c & 31;
        int s = r0 / MV;                 // VB2 | MV so block never straddles cameras
        int m0 = r0 - s * MV + rh * 16;
        size_t obase = (size_t)((s * NH + h) * MV) * DHC + dh;
#pragma unroll
        for (int ri = 0; ri < 16; ++ri) {
            valw[obase + (size_t)(m0 + ri) * DHC] = f32_to_bf16(acc[ri] + b);
        }
    }
}

// ---------------- K2: sample (2 queries/block, R8 structure) + fused out-proj ----------------
#define REDP 36   // padded red row stride (words)
__global__ __launch_bounds__(320) void k_sample2(
        const float* __restrict__ ref, const float* __restrict__ qoff,
        const float* __restrict__ aw, const void* __restrict__ bm,
        const int* __restrict__ flag, const unsigned short* __restrict__ valw,
        const float* __restrict__ Wout, const float* __restrict__ bout,
        const float* __restrict__ query, float* __restrict__ out) {
    int bid = blockIdx.x;
    int pi = (bid & 7) * (NQ / 16) + (bid >> 3);   // XCD-chunked, bijective (3200%8==0)
    int n0 = pi * 2;                                // queries n0, n0+1
    int t = threadIdx.x;

    __shared__ float qo[2][160];
    __shared__ float awl[2][NH * NP];
    __shared__ float rf[2][SC][DD][2];
    __shared__ float mk[2][SC];
    __shared__ int   pairI[NPAIR][4];     // corner bf16-element indices (clamped)
    __shared__ float pairW[NPAIR][4];     // corner weights * validity * aw
    __shared__ float red[80][REDP];       // slot-reduction buffer
    __shared__ float sl[2][CH];           // per-query slot vectors

    {
        int qq = t / 160, idx = t - qq * 160;     // 320 threads exactly
        qo[qq][idx] = qoff[(size_t)(n0 + qq) * 160 + idx];
    }
    if (t < 160) {
        int qq = t / 80, idx = t - qq * 80;
        awl[qq][idx] = aw[(size_t)(n0 + qq) * 80 + idx];
    }
    if (t >= 160 && t < 256) {
        int i = t - 160;
        int qq = i / 48, rem = i - qq * 48;
        int s = rem >> 3, r2 = rem & 7;
        rf[qq][s][r2 >> 1][r2 & 1] = ref[(size_t)(s * NQ + n0 + qq) * 8 + r2];
    }
    if (t >= 256 && t < 256 + 2 * SC) {
        int i = t - 256;
        int qq = i / SC, s = i - qq * SC;
        int gi = s * NQ + n0 + qq;
        int f = *flag;
        int any;
        if (f == 1) {
            const unsigned char* p = (const unsigned char*)bm + (size_t)gi * 4;
            any = (int)(p[0] | p[1] | p[2] | p[3]);
        } else if (f == 0) {
            const int* p = (const int*)bm + (size_t)gi * 4;
            any = p[0] | p[1] | p[2] | p[3];
        } else {
            const float* p = (const float*)bm + (size_t)gi * 4;
            any = (p[0] != 0.f) | (p[1] != 0.f) | (p[2] != 0.f) | (p[3] != 0.f);
        }
        mk[qq][s] = any ? 1.0f : 0.0f;
    }
    __syncthreads();

    for (int qq = 0; qq < 2; ++qq) {
        // ---- Phase A: coordinates / weights (cooperative, once per pair) ----
        for (int i = t; i < NPAIR; i += 320) {
            int s = i / (NH * NP);
            int q = i - s * (NH * NP);      // q = p*4 + h
            int h = q & 3;
            int p = q >> 2;
            int g = p >> 2, d = p & 3;
            float x = rf[qq][s][d][0] * (float)WSX + qo[qq][((h * NPG + g) * DD + d) * 2 + 0] - 0.5f;
            float y = rf[qq][s][d][1] * (float)HSY + qo[qq][((h * NPG + g) * DD + d) * 2 + 1] - 0.5f;
            float xf = floorf(x), yf = floorf(y);
            float wx = x - xf, wy = y - yf;
            int x0 = (int)xf, y0 = (int)yf;
            int x1 = x0 + 1, y1 = y0 + 1;
            float vx0 = (x0 >= 0 && x0 < WSX) ? 1.f : 0.f;
            float vx1 = (x1 >= 0 && x1 < WSX) ? 1.f : 0.f;
            float vy0 = (y0 >= 0 && y0 < HSY) ? 1.f : 0.f;
            float vy1 = (y1 >= 0 && y1 < HSY) ? 1.f : 0.f;
            int cx0 = min(max(x0, 0), WSX - 1), cx1 = min(max(x1, 0), WSX - 1);
            int cy0 = min(max(y0, 0), HSY - 1), cy1 = min(max(y1, 0), HSY - 1);
            int base = (s * NH + h) * MV;
            pairI[i][0] = (base + cy0 * WSX + cx0) * DHC;
            pairI[i][1] = (base + cy0 * WSX + cx1) * DHC;
            pairI[i][2] = (base + cy1 * WSX + cx0) * DHC;
            pairI[i][3] = (base + cy1 * WSX + cx1) * DHC;
            float a = awl[qq][h * NP + p];
            pairW[i][0] = (1.f - wx) * (1.f - wy) * vx0 * vy0 * a;
            pairW[i][1] = wx * (1.f - wy) * vx1 * vy0 * a;
            pairW[i][2] = (1.f - wx) * wy * vx0 * vy1 * a;
            pairW[i][3] = wx * wy * vx1 * vy1 * a;
        }
        __syncthreads();

        // ---- Phase B: bf16 gather + packed accumulate ----
        int sid = t >> 2;           // 0..79 pair slot (q = sid; h = sid & 3)
        int c8 = t & 3;             // channel octet
        int coff = c8 * 8;
        float2 acc2[4];
#pragma unroll
        for (int j = 0; j < 4; ++j) acc2[j] = make_float2(0.f, 0.f);
        for (int s = 0; s < SC; ++s) {
            if (mk[qq][s] == 0.f) continue;     // uniform per block
            int pr = s * (NH * NP) + sid;
            int4  ii = *(const int4*)pairI[pr];
            float4 ww = *(const float4*)pairW[pr];
#define CORNER(IDX, W)  {                                                     \
            uint4 u = *(const uint4*)(valw + (IDX) + coff);                   \
            float w_ = (W);                                                   \
            float2 w2 = make_float2(w_, w_);                                  \
            float2 f0 = make_float2(__uint_as_float(u.x << 16),               \
                                    __uint_as_float(u.x & 0xFFFF0000u));      \
            float2 f1 = make_float2(__uint_as_float(u.y << 16),               \
                                    __uint_as_float(u.y & 0xFFFF0000u));      \
            float2 f2 = make_float2(__uint_as_float(u.z << 16),               \
                                    __uint_as_float(u.z & 0xFFFF0000u));      \
            float2 f3 = make_float2(__uint_as_float(u.w << 16),               \
                                    __uint_as_float(u.w & 0xFFFF0000u));      \
            acc2[0] += w2 * f0; acc2[1] += w2 * f1;                           \
            acc2[2] += w2 * f2; acc2[3] += w2 * f3;                           \
        }
            CORNER(ii.x, ww.x)
            CORNER(ii.y, ww.y)
            CORNER(ii.z, ww.z)
            CORNER(ii.w, ww.w)
#undef CORNER
        }
        *(float4*)&red[sid][coff]     = make_float4(acc2[0].x, acc2[0].y, acc2[1].x, acc2[1].y);
        *(float4*)&red[sid][coff + 4] = make_float4(acc2[2].x, acc2[2].y, acc2[3].x, acc2[3].y);
        __syncthreads();

        if (t < CH) {
            int h = t >> 5, ch = t & 31;
            float sum = 0.f;
#pragma unroll
            for (int p = 0; p < NP; ++p) sum += red[p * 4 + h][ch];
            float cnt = mk[qq][0] + mk[qq][1] + mk[qq][2] + mk[qq][3] + mk[qq][4] + mk[qq][5];
            sl[qq][t] = sum / fmaxf(cnt, 1.0f);
        }
        __syncthreads();   // red/pairs reused next iteration
    }

    // ---- fused output projection + residual (both queries) ----
    if (t < 256) {
        int c = t & 127;
        int qq = t >> 7;
        float acc = 0.f;
        for (int k = 0; k < CH; ++k) acc += sl[qq][k] * Wout[k * CH + c];
        int gi = (n0 + qq) * CH + c;
        out[gi] = acc + bout[c] + query[gi];
    }
}

extern "C" void kernel_launch(void* const* d_in, const int* in_sizes, int n_in,
                              void* d_out, int out_size, void* d_ws, size_t ws_size,
                              hipStream_t stream) {
    const float* query     = (const float*)d_in[0];
    const float* value     = (const float*)d_in[2];
    const float* query_pos = (const float*)d_in[3];
    const float* refcam    = (const float*)d_in[4];
    const void*  bev_mask  = (const void*)d_in[5];
    const float* Wv    = (const float*)d_in[8];
    const float* bv    = (const float*)d_in[9];
    const float* Woff  = (const float*)d_in[10];
    const float* boff  = (const float*)d_in[11];
    const float* Wattn = (const float*)d_in[12];
    const float* battn = (const float*)d_in[13];
    const float* Wout  = (const float*)d_in[14];
    const float* bout  = (const float*)d_in[15];

    float* wsf   = (float*)d_ws;
    int*   flag  = (int*)d_ws;
    float* qoff  = wsf + WS_QOFF;
    float* aw    = wsf + WS_AW;
    unsigned short* valw = (unsigned short*)(wsf + WS_VAL);
    float* out   = (float*)d_out;

    k_mega<<<NB_MEGA, 256, 0, stream>>>((const unsigned int*)bev_mask,
                                        query, query_pos, Woff, boff, Wattn, battn,
                                        value, Wv, bv, flag, qoff, aw, valw);
    k_sample2<<<NQ / 2, 320, 0, stream>>>(refcam, qoff, aw, bev_mask, flag, valw,
                                          Wout, bout, query, out);
}

// Round 12
// 172.041 us; speedup vs baseline: 1.0859x; 1.0859x over previous
//
#include <hip/hip_runtime.h>

// Problem constants (B=1 throughout)
#define SC 6       // cameras
#define NQ 6400    // queries
#define CH 128     // channels
#define HSY 32     // feature H
#define WSX 88     // feature W
#define MV 2816    // HSY*WSX
#define NH 4       // heads
#define NP 20      // points
#define DD 4       // Z anchors (D)
#define DHC 32     // CH/NH
#define NPG 5      // NP/DD
#define NPAIR (SC * NH * NP)   // 480 (cam,head,point) pairs per query

// mega-kernel block roles (R7-proven geometry: high TLP, small LDS)
#define QB 8
#define NB_QPROJ 800           // 800 blocks * 8 queries
#define NB_VPROJ 1056          // 1056 blocks * 16 rows = 16896
#define NB_MEGA  (1 + NB_QPROJ + NB_VPROJ)

// ---------------- workspace layout (float indices) ----------------
#define WS_QOFF     38464
#define WS_AW       1062464
#define WS_VAL      1574464

__device__ __forceinline__ unsigned short f32_to_bf16(float x) {
    unsigned int u = __float_as_uint(x);
    unsigned int r = (u + 0x7FFFu + ((u >> 16) & 1u)) >> 16;   // RNE
    return (unsigned short)r;
}

// ---------------- K1: mega (detect | qproj | vproj), role by blockIdx ----------------
// Simple high-occupancy form (8 KB LDS, no weight staging); latency hidden by
// TLP (7.3 waves/SIMD) + ILP (k-loop unroll 4 -> 4 weight loads in flight).
__global__ __launch_bounds__(256) void k_mega(
        const unsigned int* __restrict__ bm,
        const float* __restrict__ q, const float* __restrict__ qpos,
        const float* __restrict__ Woff, const float* __restrict__ boff,
        const float* __restrict__ Wattn, const float* __restrict__ battn,
        const float* __restrict__ value, const float* __restrict__ Wv,
        const float* __restrict__ bv,
        int* __restrict__ flag, float* __restrict__ qoff,
        float* __restrict__ aw, unsigned short* __restrict__ valw) {
    __shared__ __align__(16) float smem[2048];   // 8 KB union
    int bid = blockIdx.x;
    int t = threadIdx.x;

    if (bid == 0) {
        // ---- detection: scan first 2048 words (safe under all 3 layouts;
        // 30% bernoulli density -> conclusive with P(fail) ~ 0.7^2048) ----
        unsigned int* r_or = (unsigned int*)smem;
        unsigned int* r_vi = r_or + 256;
        unsigned int o = 0u, v = 0u;
        for (int i = t; i < 2048; i += 256) {
            unsigned int w = bm[i];
            o |= (w & 0xFFFFFF00u);
            v |= (unsigned int)((w != 0u) & (w != 0x3F800000u));
        }
        r_or[t] = o; r_vi[t] = v;
        __syncthreads();
        for (int s = 128; s > 0; s >>= 1) {
            if (t < s) { r_or[t] |= r_or[t + s]; r_vi[t] |= r_vi[t + s]; }
            __syncthreads();
        }
        if (t == 0) {
            int f;
            if (!r_vi[0]) f = 2;          // float32 (or all-zero)
            else if (r_or[0]) f = 1;      // byte-packed bool
            else f = 0;                   // int32
            *flag = f;
        }
        return;
    }

    if (bid <= NB_QPROJ) {
        // ---- query projections + softmax ----
        float (*qs)[QB] = (float(*)[QB])smem;            // [128][8]
        float (*lg)[NH * NP] = (float(*)[NH * NP])(smem + CH * QB);  // [8][80]
        int n0 = (bid - 1) * QB;
        for (int i = t; i < QB * CH; i += 256) {
            int qi = i >> 7, k = i & 127;
            int gi = (n0 + qi) * CH + k;
            qs[k][qi] = q[gi] + qpos[gi];
        }
        __syncthreads();
        if (t < 160) {
            float acc[QB];
#pragma unroll
            for (int qi = 0; qi < QB; ++qi) acc[qi] = 0.f;
#pragma unroll 4
            for (int k = 0; k < CH; ++k) {
                float w = Woff[k * 160 + t];
                float4 a = *(const float4*)&qs[k][0];
                float4 b = *(const float4*)&qs[k][4];
                acc[0] += a.x * w; acc[1] += a.y * w; acc[2] += a.z * w; acc[3] += a.w * w;
                acc[4] += b.x * w; acc[5] += b.y * w; acc[6] += b.z * w; acc[7] += b.w * w;
            }
            float b = boff[t];
#pragma unroll
            for (int qi = 0; qi < QB; ++qi) qoff[(n0 + qi) * 160 + t] = acc[qi] + b;
        } else if (t < 240) {
            int j = t - 160;
            float acc[QB];
#pragma unroll
            for (int qi = 0; qi < QB; ++qi) acc[qi] = 0.f;
#pragma unroll 4
            for (int k = 0; k < CH; ++k) {
                float w = Wattn[k * 80 + j];
                float4 a = *(const float4*)&qs[k][0];
                float4 b = *(const float4*)&qs[k][4];
                acc[0] += a.x * w; acc[1] += a.y * w; acc[2] += a.z * w; acc[3] += a.w * w;
                acc[4] += b.x * w; acc[5] += b.y * w; acc[6] += b.z * w; acc[7] += b.w * w;
            }
            float b = battn[j];
#pragma unroll
            for (int qi = 0; qi < QB; ++qi) lg[qi][j] = acc[qi] + b;
        }
        __syncthreads();
        if (t < QB * NH) {
            int qi = t >> 2, h = t & 3;
            float mx = -1e30f;
#pragma unroll
            for (int p = 0; p < NP; ++p) mx = fmaxf(mx, lg[qi][h * NP + p]);
            float e[NP];
            float sm = 0.f;
#pragma unroll
            for (int p = 0; p < NP; ++p) { e[p] = __expf(lg[qi][h * NP + p] - mx); sm += e[p]; }
            float inv = 1.f / sm;
#pragma unroll
            for (int p = 0; p < NP; ++p) aw[(n0 + qi) * 80 + h * NP + p] = e[p] * inv;
        }
        return;
    }

    // ---- value projection -> bf16 (s,h,m,dh), 16 rows/block ----
    {
        float (*vs)[16] = (float(*)[16])smem;            // [128][16]
        int r0 = (bid - 1 - NB_QPROJ) * 16;
        for (int i = t; i < 16 * CH; i += 256) {
            int ri = i >> 7, k = i & 127;
            vs[k][ri] = value[(size_t)(r0 + ri) * CH + k];
        }
        __syncthreads();
        int c = t & 127, rh = t >> 7;    // rh: row half (0: rows 0-7, 1: rows 8-15)
        float acc[8];
#pragma unroll
        for (int ri = 0; ri < 8; ++ri) acc[ri] = 0.f;
#pragma unroll 4
        for (int k = 0; k < CH; ++k) {
            float w = Wv[k * CH + c];
            float4 a = *(const float4*)&vs[k][rh * 8];
            float4 b = *(const float4*)&vs[k][rh * 8 + 4];
            acc[0] += a.x * w; acc[1] += a.y * w; acc[2] += a.z * w; acc[3] += a.w * w;
            acc[4] += b.x * w; acc[5] += b.y * w; acc[6] += b.z * w; acc[7] += b.w * w;
        }
        float b = bv[c];
        int h = c >> 5, dh = c & 31;
        int s = r0 / MV;                 // 16 | MV so block never straddles cameras
        int m0 = r0 - s * MV + rh * 8;
        size_t obase = (size_t)((s * NH + h) * MV) * DHC + dh;
#pragma unroll
        for (int ri = 0; ri < 8; ++ri) {
            valw[obase + (size_t)(m0 + ri) * DHC] = f32_to_bf16(acc[ri] + b);
        }
    }
}

// ---------------- K2: sample (2 queries/block, R8 structure) + fused out-proj ----------------
#define REDP 36   // padded red row stride (words)
__global__ __launch_bounds__(320) void k_sample2(
        const float* __restrict__ ref, const float* __restrict__ qoff,
        const float* __restrict__ aw, const void* __restrict__ bm,
        const int* __restrict__ flag, const unsigned short* __restrict__ valw,
        const float* __restrict__ Wout, const float* __restrict__ bout,
        const float* __restrict__ query, float* __restrict__ out) {
    int bid = blockIdx.x;
    int pi = (bid & 7) * (NQ / 16) + (bid >> 3);   // XCD-chunked, bijective (3200%8==0)
    int n0 = pi * 2;                                // queries n0, n0+1
    int t = threadIdx.x;

    __shared__ float qo[2][160];
    __shared__ float awl[2][NH * NP];
    __shared__ float rf[2][SC][DD][2];
    __shared__ float mk[2][SC];
    __shared__ int   pairI[NPAIR][4];     // corner bf16-element indices (clamped)
    __shared__ float pairW[NPAIR][4];     // corner weights * validity * aw
    __shared__ float red[80][REDP];       // slot-reduction buffer
    __shared__ float sl[2][CH];           // per-query slot vectors

    {
        int qq = t / 160, idx = t - qq * 160;     // 320 threads exactly
        qo[qq][idx] = qoff[(size_t)(n0 + qq) * 160 + idx];
    }
    if (t < 160) {
        int qq = t / 80, idx = t - qq * 80;
        awl[qq][idx] = aw[(size_t)(n0 + qq) * 80 + idx];
    }
    if (t >= 160 && t < 256) {
        int i = t - 160;
        int qq = i / 48, rem = i - qq * 48;
        int s = rem >> 3, r2 = rem & 7;
        rf[qq][s][r2 >> 1][r2 & 1] = ref[(size_t)(s * NQ + n0 + qq) * 8 + r2];
    }
    if (t >= 256 && t < 256 + 2 * SC) {
        int i = t - 256;
        int qq = i / SC, s = i - qq * SC;
        int gi = s * NQ + n0 + qq;
        int f = *flag;
        int any;
        if (f == 1) {
            const unsigned char* p = (const unsigned char*)bm + (size_t)gi * 4;
            any = (int)(p[0] | p[1] | p[2] | p[3]);
        } else if (f == 0) {
            const int* p = (const int*)bm + (size_t)gi * 4;
            any = p[0] | p[1] | p[2] | p[3];
        } else {
            const float* p = (const float*)bm + (size_t)gi * 4;
            any = (p[0] != 0.f) | (p[1] != 0.f) | (p[2] != 0.f) | (p[3] != 0.f);
        }
        mk[qq][s] = any ? 1.0f : 0.0f;
    }
    __syncthreads();

    for (int qq = 0; qq < 2; ++qq) {
        // ---- Phase A: coordinates / weights (cooperative, once per pair) ----
        for (int i = t; i < NPAIR; i += 320) {
            int s = i / (NH * NP);
            int q = i - s * (NH * NP);      // q = p*4 + h
            int h = q & 3;
            int p = q >> 2;
            int g = p >> 2, d = p & 3;
            float x = rf[qq][s][d][0] * (float)WSX + qo[qq][((h * NPG + g) * DD + d) * 2 + 0] - 0.5f;
            float y = rf[qq][s][d][1] * (float)HSY + qo[qq][((h * NPG + g) * DD + d) * 2 + 1] - 0.5f;
            float xf = floorf(x), yf = floorf(y);
            float wx = x - xf, wy = y - yf;
            int x0 = (int)xf, y0 = (int)yf;
            int x1 = x0 + 1, y1 = y0 + 1;
            float vx0 = (x0 >= 0 && x0 < WSX) ? 1.f : 0.f;
            float vx1 = (x1 >= 0 && x1 < WSX) ? 1.f : 0.f;
            float vy0 = (y0 >= 0 && y0 < HSY) ? 1.f : 0.f;
            float vy1 = (y1 >= 0 && y1 < HSY) ? 1.f : 0.f;
            int cx0 = min(max(x0, 0), WSX - 1), cx1 = min(max(x1, 0), WSX - 1);
            int cy0 = min(max(y0, 0), HSY - 1), cy1 = min(max(y1, 0), HSY - 1);
            int base = (s * NH + h) * MV;
            pairI[i][0] = (base + cy0 * WSX + cx0) * DHC;
            pairI[i][1] = (base + cy0 * WSX + cx1) * DHC;
            pairI[i][2] = (base + cy1 * WSX + cx0) * DHC;
            pairI[i][3] = (base + cy1 * WSX + cx1) * DHC;
            float a = awl[qq][h * NP + p];
            pairW[i][0] = (1.f - wx) * (1.f - wy) * vx0 * vy0 * a;
            pairW[i][1] = wx * (1.f - wy) * vx1 * vy0 * a;
            pairW[i][2] = (1.f - wx) * wy * vx0 * vy1 * a;
            pairW[i][3] = wx * wy * vx1 * vy1 * a;
        }
        __syncthreads();

        // ---- Phase B: bf16 gather + packed accumulate ----
        int sid = t >> 2;           // 0..79 pair slot (q = sid; h = sid & 3)
        int c8 = t & 3;             // channel octet
        int coff = c8 * 8;
        float2 acc2[4];
#pragma unroll
        for (int j = 0; j < 4; ++j) acc2[j] = make_float2(0.f, 0.f);
        for (int s = 0; s < SC; ++s) {
            if (mk[qq][s] == 0.f) continue;     // uniform per block
            int pr = s * (NH * NP) + sid;
            int4  ii = *(const int4*)pairI[pr];
            float4 ww = *(const float4*)pairW[pr];
#define CORNER(IDX, W)  {                                                     \
            uint4 u = *(const uint4*)(valw + (IDX) + coff);                   \
            float w_ = (W);                                                   \
            float2 w2 = make_float2(w_, w_);                                  \
            float2 f0 = make_float2(__uint_as_float(u.x << 16),               \
                                    __uint_as_float(u.x & 0xFFFF0000u));      \
            float2 f1 = make_float2(__uint_as_float(u.y << 16),               \
                                    __uint_as_float(u.y & 0xFFFF0000u));      \
            float2 f2 = make_float2(__uint_as_float(u.z << 16),               \
                                    __uint_as_float(u.z & 0xFFFF0000u));      \
            float2 f3 = make_float2(__uint_as_float(u.w << 16),               \
                                    __uint_as_float(u.w & 0xFFFF0000u));      \
            acc2[0] += w2 * f0; acc2[1] += w2 * f1;                           \
            acc2[2] += w2 * f2; acc2[3] += w2 * f3;                           \
        }
            CORNER(ii.x, ww.x)
            CORNER(ii.y, ww.y)
            CORNER(ii.z, ww.z)
            CORNER(ii.w, ww.w)
#undef CORNER
        }
        *(float4*)&red[sid][coff]     = make_float4(acc2[0].x, acc2[0].y, acc2[1].x, acc2[1].y);
        *(float4*)&red[sid][coff + 4] = make_float4(acc2[2].x, acc2[2].y, acc2[3].x, acc2[3].y);
        __syncthreads();

        if (t < CH) {
            int h = t >> 5, ch = t & 31;
            float sum = 0.f;
#pragma unroll
            for (int p = 0; p < NP; ++p) sum += red[p * 4 + h][ch];
            float cnt = mk[qq][0] + mk[qq][1] + mk[qq][2] + mk[qq][3] + mk[qq][4] + mk[qq][5];
            sl[qq][t] = sum / fmaxf(cnt, 1.0f);
        }
        __syncthreads();   // red/pairs reused next iteration
    }

    // ---- fused output projection + residual (both queries) ----
    if (t < 256) {
        int c = t & 127;
        int qq = t >> 7;
        float acc = 0.f;
#pragma unroll 4
        for (int k = 0; k < CH; ++k) acc += sl[qq][k] * Wout[k * CH + c];
        int gi = (n0 + qq) * CH + c;
        out[gi] = acc + bout[c] + query[gi];
    }
}

extern "C" void kernel_launch(void* const* d_in, const int* in_sizes, int n_in,
                              void* d_out, int out_size, void* d_ws, size_t ws_size,
                              hipStream_t stream) {
    const float* query     = (const float*)d_in[0];
    const float* value     = (const float*)d_in[2];
    const float* query_pos = (const float*)d_in[3];
    const float* refcam    = (const float*)d_in[4];
    const void*  bev_mask  = (const void*)d_in[5];
    const float* Wv    = (const float*)d_in[8];
    const float* bv    = (const float*)d_in[9];
    const float* Woff  = (const float*)d_in[10];
    const float* boff  = (const float*)d_in[11];
    const float* Wattn = (const float*)d_in[12];
    const float* battn = (const float*)d_in[13];
    const float* Wout  = (const float*)d_in[14];
    const float* bout  = (const float*)d_in[15];

    float* wsf   = (float*)d_ws;
    int*   flag  = (int*)d_ws;
    float* qoff  = wsf + WS_QOFF;
    float* aw    = wsf + WS_AW;
    unsigned short* valw = (unsigned short*)(wsf + WS_VAL);
    float* out   = (float*)d_out;

    k_mega<<<NB_MEGA, 256, 0, stream>>>((const unsigned int*)bev_mask,
                                        query, query_pos, Woff, boff, Wattn, battn,
                                        value, Wv, bv, flag, qoff, aw, valw);
    k_sample2<<<NQ / 2, 320, 0, stream>>>(refcam, qoff, aw, bev_mask, flag, valw,
                                          Wout, bout, query, out);
}